// Round 5
// baseline (247.869 us; speedup 1.0000x reference)
//
#include <hip/hip_runtime.h>
#include <math.h>

// EquivariantWSSHead: V=100000 vertices, E=1600000 edges, C0=C1=16.
//
// R1..R12: zero-global-atomic bucket binning (built to avoid FLOAT global
//   atomics = CAS loops); bf16 table + 8B payload + LDS tuple-sort.
// R13..R15: fixed-point INT accumulate discovery (native ds_add); per-run
//   dur has ~95us harness floor (R19 probe).
// R16/R18: in-kernel deletions NEUTRAL => pipeline cost is structural.
// R19 PROBE: double-pipeline => kernel pipeline = 43.6us total, floor =
//   94.7us, traffic roofline ~16us. ~27us is structure: scatter's 4
//   latency-exposed barrier phases + 26MB payload round-trip + bucket.
// R20 (this round): DIRECT design, enabled by R15's int discovery --
//   native global_atomic_add_x2 (u64) was never tried (R1-R12 only
//   rejected float CAS atomics). Pipeline:
//     K1 precompute: table (bf16) + selfbuf + zero acc (V x 16B).
//     K2 edge: one coalesced pass over src/dst/ang/tr, table gather,
//        trig, TWO packed u64 global atomics per edge (bias trick:
//        low field += val*2^17 + 2^22, high field += other val / count;
//        deg<=64, |v|<32 => low sum <= 2^29, never carries).
//     K3 finalize: per-vertex unpack + sigmoid + frame projection.
//   Deletes: payload 26MB round-trip, LDS sort, histogram/scan/reserve,
//   bucket kernel. Values now fp32 until fixed-point (payload bf16
//   rounding eliminated). Falsifier: if device-scope atomic throughput
//   is the wall, dur >= 145 and we've measured the atomic rate.

#define MAXNB 400        // workspace layout keeps 391-block precompute tiling
#define FIXS 131072.0f   // 2^17 fixed-point scale
#define FIXSI (1.0f / 131072.0f)
#define BIASI (1 << 22)  // low-field bias (|v_fix| < 2^22 since |v| < 32)

typedef unsigned int uint32;
typedef unsigned long long uint64;

static __device__ __forceinline__ uint32 f2bf(float f) {
    uint32 u = __float_as_uint(f);
    return (u + 0x7FFFu + ((u >> 16) & 1u)) >> 16;   // RNE to bf16
}
static __device__ __forceinline__ uint32 pack2(float lo, float hi) {
    return f2bf(lo) | (f2bf(hi) << 16);
}
static __device__ __forceinline__ float bf_lo(uint32 u) {
    return __uint_as_float(u << 16);
}
static __device__ __forceinline__ float bf_hi(uint32 u) {
    return __uint_as_float(u & 0xFFFF0000u);
}

// K1: per-vertex dot-product table (256 rows staged in LDS, stride 49
// floats, conflict-free). Each block also zeroes its slice of acc.
__global__ __launch_bounds__(256)
void precompute_kernel(const float* __restrict__ x,
                       const float* __restrict__ w_self0,
                       const float* __restrict__ w_n00,
                       const float* __restrict__ w_n10,
                       const float* __restrict__ w_self11,
                       const float* __restrict__ w_n01,
                       const float* __restrict__ w_n11,
                       uint32* __restrict__ table,   // 8 u32/vertex
                       float* __restrict__ selfbuf,
                       uint64* __restrict__ acc,     // 2 u64/vertex
                       int V) {
    __shared__ float stage[256 * 49];   // 50KB
    int tid = threadIdx.x;
    int v0 = blockIdx.x * 256;
    int nv = min(256, V - v0);
    if (nv <= 0) return;
    // zero this block's accumulator slice (coalesced 16B stores)
    if (tid < nv) {
        uint4 z = {0u, 0u, 0u, 0u};
        *((uint4*)(acc + (size_t)(v0 + tid) * 2)) = z;
    }
    {
        const float4* x4 = (const float4*)(x + (size_t)v0 * 48);
        int n4 = nv * 12;
        for (int j = tid; j < n4; j += 256) {
            float4 f = x4[j];
            float* dp = stage + (j / 12) * 49 + (j % 12) * 4;
            dp[0] = f.x; dp[1] = f.y; dp[2] = f.z; dp[3] = f.w;
        }
    }
    __syncthreads();
    if (tid >= nv) return;
    int v = v0 + tid;
    const float* xr = stage + tid * 49;
    float d00 = 0.f, aw0 = 0.f, bw0 = 0.f, aw1 = 0.f, bw1 = 0.f;
    float d01a = 0.f, d01b = 0.f;
    float aP = 0.f, bP = 0.f, aQ = 0.f, bQ = 0.f;
    float aR = 0.f, bR = 0.f, aS = 0.f, bS = 0.f;
    float selfmag = 0.f, t1s = 0.f, t2s = 0.f;
#pragma unroll
    for (int i = 0; i < 16; ++i) {
        float x0 = xr[i];
        float a  = xr[16 + 2 * i];
        float b  = xr[17 + 2 * i];
        d00     += x0 * w_n00[i];
        selfmag += x0 * w_self0[i];
        d01a    += x0 * w_n01[i * 2 + 0];
        d01b    += x0 * w_n01[i * 2 + 1];
        float w0 = w_n10[i * 2 + 0], w1 = w_n10[i * 2 + 1];
        aw0 += a * w0;  bw0 += b * w0;
        aw1 += a * w1;  bw1 += b * w1;
        float p = w_n11[i * 4 + 0], q = w_n11[i * 4 + 1];
        float r = w_n11[i * 4 + 2], s = w_n11[i * 4 + 3];
        aP += a * p;  bP += b * p;
        aQ += a * q;  bQ += b * q;
        aR += a * r;  bR += b * r;
        aS += a * s;  bS += b * s;
        float sa_ = w_self11[i * 2 + 0], sb_ = w_self11[i * 2 + 1];
        t1s += a * sa_ - b * sb_;
        t2s += b * sa_ + a * sb_;
    }
    uint4 w0, w1;
    w0.x = pack2(d00, aw0);  w0.y = pack2(bw0, aw1);
    w0.z = pack2(bw1, d01a); w0.w = pack2(d01b, aP);
    w1.x = pack2(bP, aQ);    w1.y = pack2(bQ, aR);
    w1.z = pack2(bR, aS);    w1.w = pack2(bS, 0.f);
    uint4* tp = (uint4*)(table + (size_t)v * 8);
    tp[0] = w0;  tp[1] = w1;
    float* sf = selfbuf + (size_t)v * 4;
    sf[0] = selfmag; sf[1] = t1s; sf[2] = t2s; sf[3] = 0.f;
}

// K2: one coalesced pass over the edge streams; per edge: 32B table
// gather, trig, message math, two packed u64 global atomic adds.
__global__ __launch_bounds__(256)
void edge_kernel(const int* __restrict__ src,
                 const int* __restrict__ dst,
                 const float* __restrict__ angles,
                 const float* __restrict__ transporters,
                 const uint32* __restrict__ table,
                 uint64* __restrict__ acc,
                 int E) {
    int i0 = blockIdx.x * 256 + threadIdx.x;
    int stride = gridDim.x * 256;
    for (int e = i0; e < E; e += stride) {
        int s = src[e];
        int d = dst[e];
        float ang = angles[e];
        float trv = transporters[e];
        // native trig: args in [0, 2pi), err ~1e-6 << bf16 table err
        float st = __sinf(ang), ct = __cosf(ang);
        float sg = __sinf(trv), cg = __cosf(trv);
        float c2t = ct * ct - st * st;
        float s2t = 2.0f * st * ct;

        const uint4* tp = (const uint4*)(table + (size_t)s * 8);
        uint4 W0 = tp[0], W1 = tp[1];
        float d00 = bf_lo(W0.x), aw0 = bf_hi(W0.x);
        float bw0 = bf_lo(W0.y), aw1 = bf_hi(W0.y);
        float bw1 = bf_lo(W0.z), d01a = bf_hi(W0.z);
        float d01b = bf_lo(W0.w), aP = bf_hi(W0.w);
        float bP = bf_lo(W1.x), aQ = bf_hi(W1.x);
        float bQ = bf_lo(W1.y), aR = bf_hi(W1.y);
        float bR = bf_lo(W1.z), aS = bf_hi(W1.z);
        float bS = bf_lo(W1.w);

        float u1w0 = cg * aw0 - sg * bw0, u2w0 = sg * aw0 + cg * bw0;
        float u1w1 = cg * aw1 - sg * bw1, u2w1 = sg * aw1 + cg * bw1;
        float m0 = d00 + ct * u1w0 + st * u2w0 - st * u1w1 + ct * u2w1;

        float u1p = cg * aP - sg * bP, u2p = sg * aP + cg * bP;
        float u1q = cg * aQ - sg * bQ, u2q = sg * aQ + cg * bQ;
        float u1r = cg * aR - sg * bR, u2r = sg * aR + cg * bR;
        float u1s = cg * aS - sg * bS, u2s = sg * aS + cg * bS;

        float mv1 = d01a * ct - d01b * st
                  + u1p - u2q
                  + c2t * u1r + s2t * u2r
                  - (s2t * u1s - c2t * u2s);
        float mv2 = d01a * st + d01b * ct
                  + u2p + u1q
                  + s2t * u1r - c2t * u2r
                  + c2t * u1s + s2t * u2s;

        int m0f  = __float2int_rn(m0  * FIXS);
        int mv1f = __float2int_rn(mv1 * FIXS);
        int mv2f = __float2int_rn(mv2 * FIXS);
        uint64 pa = (uint64)(uint32)(m0f + BIASI)
                  | ((uint64)(uint32)mv1f << 32);
        uint64 pb = (uint64)(uint32)(mv2f + BIASI)
                  | (1ULL << 32);
        atomicAdd(&acc[(size_t)d * 2 + 0], pa);
        atomicAdd(&acc[(size_t)d * 2 + 1], pb);
    }
}

// K3: per-vertex unpack of the packed fixed-point sums + fused finalize.
__global__ __launch_bounds__(256)
void finalize_kernel(const uint64* __restrict__ acc,
                     const float* __restrict__ selfbuf,
                     const float* __restrict__ e1,
                     const float* __restrict__ e2,
                     float* __restrict__ out,
                     int V) {
    int v = blockIdx.x * 256 + threadIdx.x;
    if (v >= V) return;
    uint64 a = acc[(size_t)v * 2 + 0];
    uint64 b = acc[(size_t)v * 2 + 1];
    uint32 nw = (uint32)(b >> 32);
    int cnt  = (int)nw;
    int m0s  = (int)((uint32)a - nw * (uint32)BIASI);
    int mv1s = (int)(a >> 32);
    int mv2s = (int)((uint32)b - nw * (uint32)BIASI);
    float A0 = (float)m0s  * FIXSI;
    float A1 = (float)mv1s * FIXSI;
    float A2 = (float)mv2s * FIXSI;
    float inv = 1.0f / fmaxf((float)cnt, 1.0f);
    const float* sf = selfbuf + (size_t)v * 4;
    float mag = A0 * inv + sf[0];
    float t1  = A1 * inv + sf[1];
    float t2  = A2 * inv + sf[2];
    float scale = 2.0f / (1.0f + expf(-mag));
    float e1x = e1[v * 3 + 0], e1y = e1[v * 3 + 1], e1z = e1[v * 3 + 2];
    float e2x = e2[v * 3 + 0], e2y = e2[v * 3 + 1], e2z = e2[v * 3 + 2];
    out[v * 3 + 0] = (t1 * e1x + t2 * e2x) * scale;
    out[v * 3 + 1] = (t1 * e1y + t2 * e2y) * scale;
    out[v * 3 + 2] = (t1 * e1z + t2 * e2z) * scale;
}

extern "C" void kernel_launch(void* const* d_in, const int* in_sizes, int n_in,
                              void* d_out, int out_size, void* d_ws, size_t ws_size,
                              hipStream_t stream) {
    const float* x            = (const float*)d_in[0];
    const int*   edge_index   = (const int*)d_in[1];
    const float* angles       = (const float*)d_in[2];
    const float* transporters = (const float*)d_in[3];
    const float* e1           = (const float*)d_in[4];
    const float* e2           = (const float*)d_in[5];
    const float* w_self0      = (const float*)d_in[6];
    const float* w_n00        = (const float*)d_in[7];
    const float* w_n10        = (const float*)d_in[8];
    const float* w_self11     = (const float*)d_in[9];
    const float* w_n01        = (const float*)d_in[10];
    const float* w_n11        = (const float*)d_in[11];
    float* out = (float*)d_out;

    int V = in_sizes[0] / 48;
    int E = in_sizes[2];
    const int* src = edge_index;
    const int* dst = edge_index + E;

    char* p = (char*)d_ws;
    uint32* table  = (uint32*)p;  p += (size_t)V * 8 * 4;         // 3.2MB
    float* selfbuf = (float*)p;   p += (size_t)V * 4 * 4;         // 1.6MB
    p = (char*)(((uintptr_t)p + 63) & ~(uintptr_t)63);
    uint64* acc    = (uint64*)p;  p += (size_t)V * 2 * 8;         // 1.6MB

    int gv = (V + 255) / 256;                // 391

    precompute_kernel<<<gv, 256, 0, stream>>>(
        x, w_self0, w_n00, w_n10, w_self11, w_n01, w_n11,
        table, selfbuf, acc, V);
    int ge = min((E + 255) / 256, 2048);     // grid-stride, ~3 edges/thread
    edge_kernel<<<ge, 256, 0, stream>>>(src, dst, angles, transporters,
                                        table, acc, E);
    finalize_kernel<<<gv, 256, 0, stream>>>(acc, selfbuf, e1, e2, out, V);
}